// Round 3
// baseline (2071.338 us; speedup 1.0000x reference)
//
#include <hip/hip_runtime.h>

#define TSTEPS 15
#define HID    64
#define LAT    16
#define NBATCH 65536

typedef _Float16 v8h __attribute__((ext_vector_type(8)));
typedef _Float16 v4h __attribute__((ext_vector_type(4)));
typedef float    v4f __attribute__((ext_vector_type(4)));

__device__ __forceinline__ float fast_sig(float x) {
    return __builtin_amdgcn_rcpf(1.0f + __expf(-x));
}
__device__ __forceinline__ float fast_tanh(float x) {
    return 2.0f * __builtin_amdgcn_rcpf(1.0f + __expf(-2.0f * x)) - 1.0f;
}

__device__ __forceinline__ v8h vzero8() {
    v8h v;
#pragma unroll
    for (int i = 0; i < 8; ++i) v[i] = (_Float16)0.0f;
    return v;
}

// Single-pass fused 2-layer LSTM + FC. Both layers' weight A-fragments stay
// resident in LDS for the whole kernel (staged once); the t-loop touches only
// LDS + registers. h0/h1 persist in registers as B-frags; a single per-wave
// LDS buffer is the C-layout -> B-frag transpose medium (reused twice per t,
// wave-private, no barriers).
//   D[m=gate(256), n=batch(16)] = A[weights] * B[z | h0 | x | h1]
// Fragment planes in wf: 0=Wih0(z,K16 zero-padded to 32) 1,2=Whh0 3,4=Wih1 5,6=Whh1.
// Gate order (PyTorch): 0=i,1=f,2=g,3=o ; gate row g = 64*type + u, u=16a+4q+r.
__global__ __launch_bounds__(1024, 4) void lstm2_fused1(
        const float* __restrict__ z,
        const float* __restrict__ Wih0, const float* __restrict__ Whh0,
        const float* __restrict__ bih0, const float* __restrict__ bhh0,
        const float* __restrict__ Wih1, const float* __restrict__ Whh1,
        const float* __restrict__ bih1, const float* __restrict__ bhh1,
        const float* __restrict__ Wfc,  const float* __restrict__ bfc,
        float* __restrict__ out)
{
    __shared__ __align__(16) _Float16 wf[7 * 16 * 64 * 8];   // 114688 B
    __shared__ __align__(16) float    bsum[512];             //   2048 B
    __shared__ __align__(16) _Float16 state[16][16 * 72];    //  36864 B
                                                             // total 153600 B

    const int tid  = threadIdx.x;
    const int wave = tid >> 6;
    const int lane = tid & 63;
    const int q    = lane >> 4;          // quad
    const int c    = lane & 15;          // batch col within wave tile
    const int row0 = blockIdx.x * 256 + wave * 16;   // wave's batch base

    /* ---------------- one-time staging: all weights + biases ------------- */
#pragma unroll 4
    for (int e = tid; e < 7 * 16 * 64 * 8; e += 1024) {
        const int j  = e & 7;
        const int lm = (e >> 3) & 63;
        const int mt = (e >> 9) & 15;
        const int p  = e >> 13;                  // fragment plane 0..6
        const int g  = mt * 16 + (lm & 15);      // gate row 0..255
        const int kk = (lm >> 4) * 8 + j;        // k within 32-chunk
        float v;
        if (p == 0)      v = (kk < LAT) ? Wih0[g * LAT + kk] : 0.0f;
        else if (p == 1) v = Whh0[g * HID + kk];
        else if (p == 2) v = Whh0[g * HID + 32 + kk];
        else if (p == 3) v = Wih1[g * HID + kk];
        else if (p == 4) v = Wih1[g * HID + 32 + kk];
        else if (p == 5) v = Whh1[g * HID + kk];
        else             v = Whh1[g * HID + 32 + kk];
        wf[e] = (_Float16)v;
    }
    if (tid < 512)
        bsum[tid] = (tid < 256) ? bih0[tid] + bhh0[tid]
                                : bih1[tid - 256] + bhh1[tid - 256];
    __syncthreads();   // the only barrier in the kernel

    _Float16* stW = &state[wave][0];
    const float bfcv = bfc[0];

    // z B-fragment (constant over t): B[k=8q+j][c] = z[row0+c][k], k<16
    v8h zfrag = vzero8();
    if (q < 2) {
        const float* zp = z + (size_t)(row0 + c) * LAT + q * 8;
        const float4 za = *(const float4*)(zp);
        const float4 zb = *(const float4*)(zp + 4);
        zfrag[0] = (_Float16)za.x; zfrag[1] = (_Float16)za.y;
        zfrag[2] = (_Float16)za.z; zfrag[3] = (_Float16)za.w;
        zfrag[4] = (_Float16)zb.x; zfrag[5] = (_Float16)zb.y;
        zfrag[6] = (_Float16)zb.z; zfrag[7] = (_Float16)zb.w;
    }

    // FC weights, hoisted (t-invariant): wvfc[a][r] = Wfc[16a+4q+r]
    v4f wvfc[4];
#pragma unroll
    for (int a = 0; a < 4; ++a) wvfc[a] = *(const v4f*)(Wfc + 16 * a + 4 * q);

    v8h hf0 = vzero8(), hf1 = vzero8();   // h0 B-frags (u 0..31 / 32..63)
    v8h gf0 = vzero8(), gf1 = vzero8();   // h1 B-frags
    float c0s[16], c1s[16];
#pragma unroll
    for (int i = 0; i < 16; ++i) { c0s[i] = 0.0f; c1s[i] = 0.0f; }

#define AFRAG(pl, mt) (*(const v8h*)&wf[(((pl) * 16 + (mt)) * 64 + lane) * 8])

#pragma unroll 1
    for (int t = 0; t < TSTEPS; ++t) {
        /* ------------------------- layer 0 --------------------------- */
#pragma unroll
        for (int a = 0; a < 4; ++a) {            // unit group u = 16a+4q+r
            v4f acc[4];
#pragma unroll
            for (int ty = 0; ty < 4; ++ty) {
                const int mt = 4 * ty + a;
                v4f t0 = *(const v4f*)&bsum[64 * ty + 16 * a + 4 * q];  // fp32 bias
                t0 = __builtin_amdgcn_mfma_f32_16x16x32_f16(AFRAG(0, mt), zfrag, t0, 0, 0, 0);
                t0 = __builtin_amdgcn_mfma_f32_16x16x32_f16(AFRAG(1, mt), hf0,   t0, 0, 0, 0);
                t0 = __builtin_amdgcn_mfma_f32_16x16x32_f16(AFRAG(2, mt), hf1,   t0, 0, 0, 0);
                acc[ty] = t0;
            }
            v4h pk;
#pragma unroll
            for (int r = 0; r < 4; ++r) {
                const float ig = fast_sig(acc[0][r]);
                const float fg = fast_sig(acc[1][r]);
                const float gg = fast_tanh(acc[2][r]);
                const float og = fast_sig(acc[3][r]);
                const float cc = fg * c0s[a * 4 + r] + ig * gg;
                c0s[a * 4 + r] = cc;
                pk[r] = (_Float16)(og * fast_tanh(cc));
            }
            *(v4h*)&stW[c * 72 + 16 * a + 4 * q] = pk;   // 8B store, C->B medium
        }
        // read back h0' as B-frags (this is also x_t for layer 1)
        hf0 = *(const v8h*)&stW[c * 72 + 8 * q];
        hf1 = *(const v8h*)&stW[c * 72 + 32 + 8 * q];

        /* ------------------------- layer 1 + FC ---------------------- */
        float p = 0.0f;
#pragma unroll
        for (int a = 0; a < 4; ++a) {
            v4f acc[4];
#pragma unroll
            for (int ty = 0; ty < 4; ++ty) {
                const int mt = 4 * ty + a;
                v4f t0 = *(const v4f*)&bsum[256 + 64 * ty + 16 * a + 4 * q];
                t0 = __builtin_amdgcn_mfma_f32_16x16x32_f16(AFRAG(3, mt), hf0, t0, 0, 0, 0);
                t0 = __builtin_amdgcn_mfma_f32_16x16x32_f16(AFRAG(4, mt), hf1, t0, 0, 0, 0);
                t0 = __builtin_amdgcn_mfma_f32_16x16x32_f16(AFRAG(5, mt), gf0, t0, 0, 0, 0);
                t0 = __builtin_amdgcn_mfma_f32_16x16x32_f16(AFRAG(6, mt), gf1, t0, 0, 0, 0);
                acc[ty] = t0;
            }
            v4h pk;
#pragma unroll
            for (int r = 0; r < 4; ++r) {
                const float ig = fast_sig(acc[0][r]);
                const float fg = fast_sig(acc[1][r]);
                const float gg = fast_tanh(acc[2][r]);
                const float og = fast_sig(acc[3][r]);
                const float cc = fg * c1s[a * 4 + r] + ig * gg;
                c1s[a * 4 + r] = cc;
                const float hh = og * fast_tanh(cc);
                pk[r] = (_Float16)hh;
                p = fmaf(hh, wvfc[a][r], p);     // fused FC over u
            }
            *(v4h*)&stW[c * 72 + 16 * a + 4 * q] = pk;
        }
        gf0 = *(const v8h*)&stW[c * 72 + 8 * q];
        gf1 = *(const v8h*)&stW[c * 72 + 32 + 8 * q];

        // reduce FC partial across the 4 quads (u-space), store
        p += __shfl_xor(p, 16);
        p += __shfl_xor(p, 32);
        if (lane < 16)
            out[(size_t)(row0 + lane) * TSTEPS + t] = p + bfcv;
    }
#undef AFRAG
}

extern "C" void kernel_launch(void* const* d_in, const int* in_sizes, int n_in,
                              void* d_out, int out_size, void* d_ws, size_t ws_size,
                              hipStream_t stream)
{
    (void)in_sizes; (void)n_in; (void)out_size; (void)d_ws; (void)ws_size;

    const float* z    = (const float*)d_in[0];
    const float* Wih0 = (const float*)d_in[1];
    const float* Whh0 = (const float*)d_in[2];
    const float* bih0 = (const float*)d_in[3];
    const float* bhh0 = (const float*)d_in[4];
    const float* Wih1 = (const float*)d_in[5];
    const float* Whh1 = (const float*)d_in[6];
    const float* bih1 = (const float*)d_in[7];
    const float* bhh1 = (const float*)d_in[8];
    const float* Wfc  = (const float*)d_in[9];
    const float* bfc  = (const float*)d_in[10];

    lstm2_fused1<<<dim3(NBATCH / 256), dim3(1024), 0, stream>>>(
        z, Wih0, Whh0, bih0, bhh0, Wih1, Whh1, bih1, bhh1, Wfc, bfc,
        (float*)d_out);
}

// Round 4
// 2068.488 us; speedup vs baseline: 1.0014x; 1.0014x over previous
//
#include <hip/hip_runtime.h>

#define TSTEPS 15
#define HID    64
#define LAT    16
#define NBATCH 65536

typedef _Float16 v8h __attribute__((ext_vector_type(8)));
typedef _Float16 v4h __attribute__((ext_vector_type(4)));
typedef float    v4f __attribute__((ext_vector_type(4)));

__device__ __forceinline__ float fast_sig(float x) {
    return __builtin_amdgcn_rcpf(1.0f + __expf(-x));
}
__device__ __forceinline__ float fast_tanh(float x) {
    return 2.0f * __builtin_amdgcn_rcpf(1.0f + __expf(-2.0f * x)) - 1.0f;
}

__device__ __forceinline__ v8h vzero8() {
    v8h v;
#pragma unroll
    for (int i = 0; i < 8; ++i) v[i] = (_Float16)0.0f;
    return v;
}

// Single-pass fused 2-layer LSTM + FC. Both layers' weight A-fragments stay
// resident in LDS for the whole kernel (staged once); the t-loop touches only
// LDS + registers. h0/h1 persist in registers as B-frags; a per-wave LDS
// buffer is the C-layout -> B-frag transpose medium (wave-private, no
// barriers after staging).
//   D[m=gate(256), n=batch(16)] = A[weights] * B[z | h0 | x | h1]
// wf planes: 0=Wih0(z,K16 zero-padded) 1,2=Whh0 3,4=Wih1 5,6=Whh1.
// Gate order (PyTorch): 0=i,1=f,2=g,3=o ; g = 64*type + u, u=16a+4q+r.
//
// __launch_bounds__(1024, 1): a 1024-thread block forces all 16 waves
// co-resident (4/SIMD) -> compiler caps VGPR at 128. Round-3's (1024,4)
// made it cap at 64 -> scratch spill (4.2 GB FETCH) -> 2.5x regression.
__global__ __launch_bounds__(1024, 1) void lstm2_fused1(
        const float* __restrict__ z,
        const float* __restrict__ Wih0, const float* __restrict__ Whh0,
        const float* __restrict__ bih0, const float* __restrict__ bhh0,
        const float* __restrict__ Wih1, const float* __restrict__ Whh1,
        const float* __restrict__ bih1, const float* __restrict__ bhh1,
        const float* __restrict__ Wfc,  const float* __restrict__ bfc,
        float* __restrict__ out)
{
    __shared__ __align__(16) _Float16 wf[7 * 16 * 64 * 8];   // 114688 B
    __shared__ __align__(16) float    bsum[512];             //   2048 B
    __shared__ __align__(16) float    wfcs[64];              //    256 B
    __shared__ __align__(16) _Float16 state[16][16 * 72];    //  36864 B
                                                             // ~153856 B total

    const int tid  = threadIdx.x;
    const int wave = tid >> 6;
    const int lane = tid & 63;
    const int q    = lane >> 4;          // quad
    const int c    = lane & 15;          // batch col within wave tile
    const int row0 = blockIdx.x * 256 + wave * 16;   // wave's batch base

    /* ---------------- one-time staging: all weights + biases ------------- */
#pragma unroll 4
    for (int e = tid; e < 7 * 16 * 64 * 8; e += 1024) {
        const int j  = e & 7;
        const int lm = (e >> 3) & 63;
        const int mt = (e >> 9) & 15;
        const int p  = e >> 13;                  // fragment plane 0..6
        const int g  = mt * 16 + (lm & 15);      // gate row 0..255
        const int kk = (lm >> 4) * 8 + j;        // k within 32-chunk
        float v;
        if (p == 0)      v = (kk < LAT) ? Wih0[g * LAT + kk] : 0.0f;
        else if (p == 1) v = Whh0[g * HID + kk];
        else if (p == 2) v = Whh0[g * HID + 32 + kk];
        else if (p == 3) v = Wih1[g * HID + kk];
        else if (p == 4) v = Wih1[g * HID + 32 + kk];
        else if (p == 5) v = Whh1[g * HID + kk];
        else             v = Whh1[g * HID + 32 + kk];
        wf[e] = (_Float16)v;
    }
    if (tid < 512)
        bsum[tid] = (tid < 256) ? bih0[tid] + bhh0[tid]
                                : bih1[tid - 256] + bhh1[tid - 256];
    if (tid < 64) wfcs[tid] = Wfc[tid];
    __syncthreads();   // the only barrier in the kernel

    _Float16* stW = &state[wave][0];
    const float bfcv = bfc[0];

    // z B-fragment (constant over t): B[k=8q+j][c] = z[row0+c][k], k<16
    v8h zfrag = vzero8();
    if (q < 2) {
        const float* zp = z + (size_t)(row0 + c) * LAT + q * 8;
        const float4 za = *(const float4*)(zp);
        const float4 zb = *(const float4*)(zp + 4);
        zfrag[0] = (_Float16)za.x; zfrag[1] = (_Float16)za.y;
        zfrag[2] = (_Float16)za.z; zfrag[3] = (_Float16)za.w;
        zfrag[4] = (_Float16)zb.x; zfrag[5] = (_Float16)zb.y;
        zfrag[6] = (_Float16)zb.z; zfrag[7] = (_Float16)zb.w;
    }

    v8h hf0 = vzero8(), hf1 = vzero8();   // h0 B-frags (u 0..31 / 32..63)
    v8h gf0 = vzero8(), gf1 = vzero8();   // h1 B-frags
    float c0s[16], c1s[16];
#pragma unroll
    for (int i = 0; i < 16; ++i) { c0s[i] = 0.0f; c1s[i] = 0.0f; }

#define AFRAG(pl, mt) (*(const v8h*)&wf[(((pl) * 16 + (mt)) * 64 + lane) * 8])

#pragma unroll 1
    for (int t = 0; t < TSTEPS; ++t) {
        /* ------------------------- layer 0 --------------------------- */
#pragma unroll
        for (int a = 0; a < 4; ++a) {            // unit group u = 16a+4q+r
            v4f acc[4];
#pragma unroll
            for (int ty = 0; ty < 4; ++ty) {
                const int mt = 4 * ty + a;
                v4f t0 = *(const v4f*)&bsum[64 * ty + 16 * a + 4 * q];  // fp32 bias
                t0 = __builtin_amdgcn_mfma_f32_16x16x32_f16(AFRAG(0, mt), zfrag, t0, 0, 0, 0);
                t0 = __builtin_amdgcn_mfma_f32_16x16x32_f16(AFRAG(1, mt), hf0,   t0, 0, 0, 0);
                t0 = __builtin_amdgcn_mfma_f32_16x16x32_f16(AFRAG(2, mt), hf1,   t0, 0, 0, 0);
                acc[ty] = t0;
            }
            v4h pk;
#pragma unroll
            for (int r = 0; r < 4; ++r) {
                const float ig = fast_sig(acc[0][r]);
                const float fg = fast_sig(acc[1][r]);
                const float gg = fast_tanh(acc[2][r]);
                const float og = fast_sig(acc[3][r]);
                const float cc = fg * c0s[a * 4 + r] + ig * gg;
                c0s[a * 4 + r] = cc;
                pk[r] = (_Float16)(og * fast_tanh(cc));
            }
            *(v4h*)&stW[c * 72 + 16 * a + 4 * q] = pk;   // 8B store, C->B medium
        }
        // read back h0' as B-frags (this is also x_t for layer 1)
        hf0 = *(const v8h*)&stW[c * 72 + 8 * q];
        hf1 = *(const v8h*)&stW[c * 72 + 32 + 8 * q];

        /* ------------------------- layer 1 + FC ---------------------- */
        float p = 0.0f;
#pragma unroll
        for (int a = 0; a < 4; ++a) {
            v4f acc[4];
#pragma unroll
            for (int ty = 0; ty < 4; ++ty) {
                const int mt = 4 * ty + a;
                v4f t0 = *(const v4f*)&bsum[256 + 64 * ty + 16 * a + 4 * q];
                t0 = __builtin_amdgcn_mfma_f32_16x16x32_f16(AFRAG(3, mt), hf0, t0, 0, 0, 0);
                t0 = __builtin_amdgcn_mfma_f32_16x16x32_f16(AFRAG(4, mt), hf1, t0, 0, 0, 0);
                t0 = __builtin_amdgcn_mfma_f32_16x16x32_f16(AFRAG(5, mt), gf0, t0, 0, 0, 0);
                t0 = __builtin_amdgcn_mfma_f32_16x16x32_f16(AFRAG(6, mt), gf1, t0, 0, 0, 0);
                acc[ty] = t0;
            }
            const v4f wv = *(const v4f*)&wfcs[16 * a + 4 * q];  // FC wts from LDS
            v4h pk;
#pragma unroll
            for (int r = 0; r < 4; ++r) {
                const float ig = fast_sig(acc[0][r]);
                const float fg = fast_sig(acc[1][r]);
                const float gg = fast_tanh(acc[2][r]);
                const float og = fast_sig(acc[3][r]);
                const float cc = fg * c1s[a * 4 + r] + ig * gg;
                c1s[a * 4 + r] = cc;
                const float hh = og * fast_tanh(cc);
                pk[r] = (_Float16)hh;
                p = fmaf(hh, wv[r], p);          // fused FC over u
            }
            *(v4h*)&stW[c * 72 + 16 * a + 4 * q] = pk;
        }
        gf0 = *(const v8h*)&stW[c * 72 + 8 * q];
        gf1 = *(const v8h*)&stW[c * 72 + 32 + 8 * q];

        // reduce FC partial across the 4 quads (u-space), store
        p += __shfl_xor(p, 16);
        p += __shfl_xor(p, 32);
        if (lane < 16)
            out[(size_t)(row0 + lane) * TSTEPS + t] = p + bfcv;
    }
#undef AFRAG
}

extern "C" void kernel_launch(void* const* d_in, const int* in_sizes, int n_in,
                              void* d_out, int out_size, void* d_ws, size_t ws_size,
                              hipStream_t stream)
{
    (void)in_sizes; (void)n_in; (void)out_size; (void)d_ws; (void)ws_size;

    const float* z    = (const float*)d_in[0];
    const float* Wih0 = (const float*)d_in[1];
    const float* Whh0 = (const float*)d_in[2];
    const float* bih0 = (const float*)d_in[3];
    const float* bhh0 = (const float*)d_in[4];
    const float* Wih1 = (const float*)d_in[5];
    const float* Whh1 = (const float*)d_in[6];
    const float* bih1 = (const float*)d_in[7];
    const float* bhh1 = (const float*)d_in[8];
    const float* Wfc  = (const float*)d_in[9];
    const float* bfc  = (const float*)d_in[10];

    lstm2_fused1<<<dim3(NBATCH / 256), dim3(1024), 0, stream>>>(
        z, Wih0, Whh0, bih0, bhh0, Wih1, Whh1, bih1, bhh1, Wfc, bfc,
        (float*)d_out);
}

// Round 5
// 1476.602 us; speedup vs baseline: 1.4028x; 1.4008x over previous
//
#include <hip/hip_runtime.h>

#define TSTEPS 15
#define HID    64
#define LAT    16
#define NBATCH 65536

typedef _Float16 v8h __attribute__((ext_vector_type(8)));
typedef _Float16 v4h __attribute__((ext_vector_type(4)));
typedef float    v4f __attribute__((ext_vector_type(4)));

__device__ __forceinline__ float fast_sig(float x) {
    return __builtin_amdgcn_rcpf(1.0f + __expf(-x));
}
__device__ __forceinline__ float fast_tanh(float x) {
    return 2.0f * __builtin_amdgcn_rcpf(1.0f + __expf(-2.0f * x)) - 1.0f;
}

__device__ __forceinline__ v8h vzero8() {
    v8h v;
#pragma unroll
    for (int i = 0; i < 8; ++i) v[i] = (_Float16)0.0f;
    return v;
}

// Single-pass fused 2-layer LSTM + FC. Both layers' weight A-fragments stay
// resident in LDS for the whole kernel (staged once); the t-loop touches only
// LDS + registers.
//
// Block size 512 (8 waves), NOT 1024: rounds 3/4 showed 1024-thread blocks
// get a 64-arch-VGPR allocation (forced 4 waves/SIMD -> 128 unified regs,
// split ~64 arch + 64 acc) -> c-state spills to scratch (4.2 GB FETCH).
// At 512 threads with __launch_bounds__(512,2): 1 block/CU (LDS-bound),
// 2 waves/SIMD, VGPR cap 256 -> no spill (round-2's near-identical body fit
// in 128). Total VALU work per SIMD is the same either way (workload is
// transcendental-bound), so nothing is lost vs 1024 threads.
//
//   D[m=gate(256), n=batch(16)] = A[weights] * B[z | h0 | x | h1]
// wf planes: 0=Wih0(z,K16 zero-padded) 1,2=Whh0 3,4=Wih1 5,6=Whh1.
// Gate order (PyTorch): 0=i,1=f,2=g,3=o ; g = 64*type + u, u=16a+4q+r.
__global__ __launch_bounds__(512, 2) void lstm2_fused1(
        const float* __restrict__ z,
        const float* __restrict__ Wih0, const float* __restrict__ Whh0,
        const float* __restrict__ bih0, const float* __restrict__ bhh0,
        const float* __restrict__ Wih1, const float* __restrict__ Whh1,
        const float* __restrict__ bih1, const float* __restrict__ bhh1,
        const float* __restrict__ Wfc,  const float* __restrict__ bfc,
        float* __restrict__ out)
{
    __shared__ __align__(16) _Float16 wf[7 * 16 * 64 * 8];   // 114688 B
    __shared__ __align__(16) float    bsum[512];             //   2048 B
    __shared__ __align__(16) float    wfcs[64];              //    256 B
    __shared__ __align__(16) _Float16 state[8][16 * 72];     //  18432 B
                                                             // ~135424 B total

    const int tid  = threadIdx.x;
    const int wave = tid >> 6;           // 0..7
    const int lane = tid & 63;
    const int q    = lane >> 4;          // quad
    const int c    = lane & 15;          // batch col within wave tile
    const int row0 = blockIdx.x * 128 + wave * 16;   // wave's batch base

    /* ---------------- one-time staging: all weights + biases ------------- */
#pragma unroll 4
    for (int e = tid; e < 7 * 16 * 64 * 8; e += 512) {
        const int j  = e & 7;
        const int lm = (e >> 3) & 63;
        const int mt = (e >> 9) & 15;
        const int p  = e >> 13;                  // fragment plane 0..6
        const int g  = mt * 16 + (lm & 15);      // gate row 0..255
        const int kk = (lm >> 4) * 8 + j;        // k within 32-chunk
        float v;
        if (p == 0)      v = (kk < LAT) ? Wih0[g * LAT + kk] : 0.0f;
        else if (p == 1) v = Whh0[g * HID + kk];
        else if (p == 2) v = Whh0[g * HID + 32 + kk];
        else if (p == 3) v = Wih1[g * HID + kk];
        else if (p == 4) v = Wih1[g * HID + 32 + kk];
        else if (p == 5) v = Whh1[g * HID + kk];
        else             v = Whh1[g * HID + 32 + kk];
        wf[e] = (_Float16)v;
    }
    bsum[tid] = (tid < 256) ? bih0[tid] + bhh0[tid]
                            : bih1[tid - 256] + bhh1[tid - 256];
    if (tid < 64) wfcs[tid] = Wfc[tid];
    __syncthreads();   // the only barrier in the kernel

    _Float16* stW = &state[wave][0];
    const float bfcv = bfc[0];

    // z B-fragment (constant over t): B[k=8q+j][c] = z[row0+c][k], k<16
    v8h zfrag = vzero8();
    if (q < 2) {
        const float* zp = z + (size_t)(row0 + c) * LAT + q * 8;
        const float4 za = *(const float4*)(zp);
        const float4 zb = *(const float4*)(zp + 4);
        zfrag[0] = (_Float16)za.x; zfrag[1] = (_Float16)za.y;
        zfrag[2] = (_Float16)za.z; zfrag[3] = (_Float16)za.w;
        zfrag[4] = (_Float16)zb.x; zfrag[5] = (_Float16)zb.y;
        zfrag[6] = (_Float16)zb.z; zfrag[7] = (_Float16)zb.w;
    }

    v8h hf0 = vzero8(), hf1 = vzero8();   // h0 B-frags (u 0..31 / 32..63)
    v8h gf0 = vzero8(), gf1 = vzero8();   // h1 B-frags
    float c0s[16], c1s[16];
#pragma unroll
    for (int i = 0; i < 16; ++i) { c0s[i] = 0.0f; c1s[i] = 0.0f; }

#define AFRAG(pl, mt) (*(const v8h*)&wf[(((pl) * 16 + (mt)) * 64 + lane) * 8])

#pragma unroll 1
    for (int t = 0; t < TSTEPS; ++t) {
        /* ------------------------- layer 0 --------------------------- */
#pragma unroll
        for (int a = 0; a < 4; ++a) {            // unit group u = 16a+4q+r
            v4f acc[4];
#pragma unroll
            for (int ty = 0; ty < 4; ++ty) {
                const int mt = 4 * ty + a;
                v4f t0 = *(const v4f*)&bsum[64 * ty + 16 * a + 4 * q];  // fp32 bias
                t0 = __builtin_amdgcn_mfma_f32_16x16x32_f16(AFRAG(0, mt), zfrag, t0, 0, 0, 0);
                t0 = __builtin_amdgcn_mfma_f32_16x16x32_f16(AFRAG(1, mt), hf0,   t0, 0, 0, 0);
                t0 = __builtin_amdgcn_mfma_f32_16x16x32_f16(AFRAG(2, mt), hf1,   t0, 0, 0, 0);
                acc[ty] = t0;
            }
            v4h pk;
#pragma unroll
            for (int r = 0; r < 4; ++r) {
                const float ig = fast_sig(acc[0][r]);
                const float fg = fast_sig(acc[1][r]);
                const float gg = fast_tanh(acc[2][r]);
                const float og = fast_sig(acc[3][r]);
                const float cc = fg * c0s[a * 4 + r] + ig * gg;
                c0s[a * 4 + r] = cc;
                pk[r] = (_Float16)(og * fast_tanh(cc));
            }
            *(v4h*)&stW[c * 72 + 16 * a + 4 * q] = pk;   // 8B store, C->B medium
        }
        // read back h0' as B-frags (this is also x_t for layer 1)
        hf0 = *(const v8h*)&stW[c * 72 + 8 * q];
        hf1 = *(const v8h*)&stW[c * 72 + 32 + 8 * q];

        /* ------------------------- layer 1 + FC ---------------------- */
        float p = 0.0f;
#pragma unroll
        for (int a = 0; a < 4; ++a) {
            v4f acc[4];
#pragma unroll
            for (int ty = 0; ty < 4; ++ty) {
                const int mt = 4 * ty + a;
                v4f t0 = *(const v4f*)&bsum[256 + 64 * ty + 16 * a + 4 * q];
                t0 = __builtin_amdgcn_mfma_f32_16x16x32_f16(AFRAG(3, mt), hf0, t0, 0, 0, 0);
                t0 = __builtin_amdgcn_mfma_f32_16x16x32_f16(AFRAG(4, mt), hf1, t0, 0, 0, 0);
                t0 = __builtin_amdgcn_mfma_f32_16x16x32_f16(AFRAG(5, mt), gf0, t0, 0, 0, 0);
                t0 = __builtin_amdgcn_mfma_f32_16x16x32_f16(AFRAG(6, mt), gf1, t0, 0, 0, 0);
                acc[ty] = t0;
            }
            const v4f wv = *(const v4f*)&wfcs[16 * a + 4 * q];  // FC wts from LDS
            v4h pk;
#pragma unroll
            for (int r = 0; r < 4; ++r) {
                const float ig = fast_sig(acc[0][r]);
                const float fg = fast_sig(acc[1][r]);
                const float gg = fast_tanh(acc[2][r]);
                const float og = fast_sig(acc[3][r]);
                const float cc = fg * c1s[a * 4 + r] + ig * gg;
                c1s[a * 4 + r] = cc;
                const float hh = og * fast_tanh(cc);
                pk[r] = (_Float16)hh;
                p = fmaf(hh, wv[r], p);          // fused FC over u
            }
            *(v4h*)&stW[c * 72 + 16 * a + 4 * q] = pk;
        }
        gf0 = *(const v8h*)&stW[c * 72 + 8 * q];
        gf1 = *(const v8h*)&stW[c * 72 + 32 + 8 * q];

        // reduce FC partial across the 4 quads (u-space), store
        p += __shfl_xor(p, 16);
        p += __shfl_xor(p, 32);
        if (lane < 16)
            out[(size_t)(row0 + lane) * TSTEPS + t] = p + bfcv;
    }
#undef AFRAG
}

extern "C" void kernel_launch(void* const* d_in, const int* in_sizes, int n_in,
                              void* d_out, int out_size, void* d_ws, size_t ws_size,
                              hipStream_t stream)
{
    (void)in_sizes; (void)n_in; (void)out_size; (void)d_ws; (void)ws_size;

    const float* z    = (const float*)d_in[0];
    const float* Wih0 = (const float*)d_in[1];
    const float* Whh0 = (const float*)d_in[2];
    const float* bih0 = (const float*)d_in[3];
    const float* bhh0 = (const float*)d_in[4];
    const float* Wih1 = (const float*)d_in[5];
    const float* Whh1 = (const float*)d_in[6];
    const float* bih1 = (const float*)d_in[7];
    const float* bhh1 = (const float*)d_in[8];
    const float* Wfc  = (const float*)d_in[9];
    const float* bfc  = (const float*)d_in[10];

    lstm2_fused1<<<dim3(NBATCH / 128), dim3(512), 0, stream>>>(
        z, Wih0, Whh0, bih0, bhh0, Wih1, Whh1, bih1, bhh1, Wfc, bfc,
        (float*)d_out);
}